// Round 8
// baseline (293.321 us; speedup 1.0000x reference)
//
#include <hip/hip_runtime.h>
#include <math.h>

// Problem dims
#define BSZ   256
#define LDIM  128
#define PDIM  3
#define HDIM  512
#define DDIM  32
#define NDIM  50
#define NEDGE 1225   // N*(N-1)/2
#define EOUT  5      // EDIM+1
#define CH    64     // edge chunk cols
#define NRH   4      // r-splits

// out layout (floats)
//   node_logits  [256,50,32]   @ 0        (409600)
//   edge_logits  [256,1225,5]  @ 409600   (1568000)
//   size_probs   [256,50]      @ 1977600  (12800)
//   edge_indices [1225,2]      @ 1990400  (2450, float values)
// ws layout (floats): u @0 (131072), pW1 @131072 (25600), n1 @156672 (131072),
//                     P @287744 (4 x 1568000 = 6272000)

// ============ k_pre: roles {h->n1 (2b), h->u (2b), h->size (4b), pW1} =====
// grid 333 x 512.
__global__ __launch_bounds__(512) void k_pre(
        const float* __restrict__ z, const float* __restrict__ tp,
        const float* __restrict__ W_in, const float* __restrict__ b_in,
        const float* __restrict__ W_s1, const float* __restrict__ b_s1,
        const float* __restrict__ W_s2, const float* __restrict__ b_s2,
        const float* __restrict__ W_n1, const float* __restrict__ b_n1,
        const float* __restrict__ W_e1, const float* __restrict__ pe,
        float* __restrict__ n1, float* __restrict__ u,
        float* __restrict__ pW1, float* __restrict__ out_sp) {
    int bx = blockIdx.x, t = threadIdx.x;
    __shared__ float sA[4][HDIM];
    __shared__ float sB[4][HDIM];

    if (bx < 256) {
        // ---- role n1 (bx<128) or u (bx<256): 2 batches per block ----------
        int role = bx >> 7;            // 0: n1, 1: u
        int b0 = (bx & 127) * 2;
        float* sin_ = &sB[0][0];       // 262 floats
        for (int idx = t; idx < 2 * 131; idx += 512) {
            int bi = idx / 131, k = idx % 131;
            sin_[idx] = (k < LDIM) ? z[(size_t)(b0 + bi) * LDIM + k]
                                   : tp[(size_t)(b0 + bi) * PDIM + (k - LDIM)];
        }
        __syncthreads();
        {
            float bin = b_in[t];
            float a0 = bin, a1 = bin;
            for (int k = 0; k < LDIM + PDIM; ++k) {
                float w = W_in[(size_t)k * HDIM + t];
                a0 += sin_[k] * w;
                a1 += sin_[131 + k] * w;
            }
            sA[0][t] = fmaxf(a0, 0.f);
            sA[1][t] = fmaxf(a1, 0.f);
        }
        __syncthreads();
        const float* W = (role == 0) ? W_n1 : W_e1;   // W1h = rows 0..511 of W_e1
        float a0 = 0.f, a1 = 0.f;
        for (int k4 = 0; k4 < HDIM / 4; ++k4) {
            float w0 = W[(size_t)(k4 * 4 + 0) * HDIM + t];
            float w1 = W[(size_t)(k4 * 4 + 1) * HDIM + t];
            float w2 = W[(size_t)(k4 * 4 + 2) * HDIM + t];
            float w3 = W[(size_t)(k4 * 4 + 3) * HDIM + t];
            float4 x0 = *reinterpret_cast<const float4*>(&sA[0][k4 * 4]);
            float4 x1 = *reinterpret_cast<const float4*>(&sA[1][k4 * 4]);
            a0 += x0.x * w0 + x0.y * w1 + x0.z * w2 + x0.w * w3;
            a1 += x1.x * w0 + x1.y * w1 + x1.z * w2 + x1.w * w3;
        }
        if (role == 0) {
            float bb = b_n1[t];
            n1[(size_t)(b0 + 0) * HDIM + t] = fmaxf(a0 + bb, 0.f);
            n1[(size_t)(b0 + 1) * HDIM + t] = fmaxf(a1 + bb, 0.f);
        } else {
            u[(size_t)(b0 + 0) * HDIM + t] = a0;
            u[(size_t)(b0 + 1) * HDIM + t] = a1;
        }
    } else if (bx < 320) {
        // ---- role size head: 4 batches ------------------------------------
        int b0 = (bx - 256) * 4;
        float* sin_ = &sB[0][0];       // 524 floats
        for (int idx = t; idx < 4 * 131; idx += 512) {
            int bi = idx / 131, k = idx % 131;
            sin_[idx] = (k < LDIM) ? z[(size_t)(b0 + bi) * LDIM + k]
                                   : tp[(size_t)(b0 + bi) * PDIM + (k - LDIM)];
        }
        __syncthreads();
        {
            float bin = b_in[t];
            float a0 = bin, a1 = bin, a2 = bin, a3 = bin;
            for (int k = 0; k < LDIM + PDIM; ++k) {
                float w = W_in[(size_t)k * HDIM + t];
                a0 += sin_[0 * 131 + k] * w;
                a1 += sin_[1 * 131 + k] * w;
                a2 += sin_[2 * 131 + k] * w;
                a3 += sin_[3 * 131 + k] * w;
            }
            sA[0][t] = fmaxf(a0, 0.f); sA[1][t] = fmaxf(a1, 0.f);
            sA[2][t] = fmaxf(a2, 0.f); sA[3][t] = fmaxf(a3, 0.f);
        }
        __syncthreads();
        float* s1b = &sB[0][0];    // [4][256]
        float* slg = &sB[2][0];    // [4][50]
        {
            int c = t & 255, bp = t >> 8;   // batches 2bp, 2bp+1
            float bv = b_s1[c];
            float a0 = bv, a1 = bv;
            for (int k = 0; k < HDIM; ++k) {
                float w = W_s1[(size_t)k * (HDIM / 2) + c];
                a0 += sA[2 * bp][k] * w;
                a1 += sA[2 * bp + 1][k] * w;
            }
            __syncthreads();
            s1b[(2 * bp) * 256 + c] = fmaxf(a0, 0.f);
            s1b[(2 * bp + 1) * 256 + c] = fmaxf(a1, 0.f);
        }
        __syncthreads();
        int b4 = t / NDIM, o = t % NDIM;
        if (t < 4 * NDIM) {
            float a = b_s2[o];
            for (int k = 0; k < HDIM / 2; ++k)
                a += s1b[b4 * 256 + k] * W_s2[(size_t)k * NDIM + o];
            slg[b4 * NDIM + o] = a;
        }
        __syncthreads();
        if (t < 4 * NDIM) {
            float m = slg[b4 * NDIM];
            for (int k = 1; k < NDIM; ++k) m = fmaxf(m, slg[b4 * NDIM + k]);
            float s = 0.f;
            for (int k = 0; k < NDIM; ++k) s += expf(slg[b4 * NDIM + k] - m);
            out_sp[(size_t)(b0 + b4) * NDIM + o] = expf(slg[b4 * NDIM + o] - m) / s;
        }
    } else {
        // ---- role pW1: 0.5 * pe @ W1h, 4 rows -----------------------------
        int r0 = (bx - 320) * 4;
        int r[4];
#pragma unroll
        for (int q = 0; q < 4; ++q) { int rr = r0 + q; r[q] = (rr < NDIM) ? rr : NDIM - 1; }
        for (int idx = t; idx < 4 * HDIM; idx += 512)
            sA[idx >> 9][idx & 511] = pe[(size_t)r[idx >> 9] * HDIM + (idx & 511)];
        __syncthreads();
        float a0 = 0.f, a1 = 0.f, a2 = 0.f, a3 = 0.f;
        for (int k4 = 0; k4 < HDIM / 4; ++k4) {
            float w0 = W_e1[(size_t)(k4 * 4 + 0) * HDIM + t];
            float w1 = W_e1[(size_t)(k4 * 4 + 1) * HDIM + t];
            float w2 = W_e1[(size_t)(k4 * 4 + 2) * HDIM + t];
            float w3 = W_e1[(size_t)(k4 * 4 + 3) * HDIM + t];
            float4 x0 = *reinterpret_cast<const float4*>(&sA[0][k4 * 4]);
            float4 x1 = *reinterpret_cast<const float4*>(&sA[1][k4 * 4]);
            float4 x2 = *reinterpret_cast<const float4*>(&sA[2][k4 * 4]);
            float4 x3 = *reinterpret_cast<const float4*>(&sA[3][k4 * 4]);
            a0 += x0.x * w0 + x0.y * w1 + x0.z * w2 + x0.w * w3;
            a1 += x1.x * w0 + x1.y * w1 + x1.z * w2 + x1.w * w3;
            a2 += x2.x * w0 + x2.y * w1 + x2.z * w2 + x2.w * w3;
            a3 += x3.x * w0 + x3.y * w1 + x3.z * w2 + x3.w * w3;
        }
        pW1[(size_t)r[0] * HDIM + t] = 0.5f * a0;
        pW1[(size_t)r[1] * HDIM + t] = 0.5f * a1;
        pW1[(size_t)r[2] * HDIM + t] = 0.5f * a2;
        pW1[(size_t)r[3] * HDIM + t] = 0.5f * a3;
    }
}

// ============ k_nl: [256,512]@[512,1600]+b, 8 batches/block ================
// grid (32,5): W_n2 column reads amortized over 8 batches.
__global__ __launch_bounds__(320) void k_nl(const float* __restrict__ n1,
                                            const float* __restrict__ W_n2,
                                            const float* __restrict__ b_n2,
                                            float* __restrict__ out_nl) {
    const int NOUT = NDIM * DDIM;   // 1600
    int t = threadIdx.x;
    int j = blockIdx.y * 320 + t;
    int bg = blockIdx.x;            // 8 batches
    __shared__ float s[8 * HDIM];
    for (int idx = t; idx < 8 * HDIM / 4; idx += 320) {
        int lin = idx * 4;
        int row = lin >> 9, col = lin & 511;
        *reinterpret_cast<float4*>(&s[row * HDIM + col]) =
            *reinterpret_cast<const float4*>(&n1[(size_t)(bg * 8 + row) * HDIM + col]);
    }
    __syncthreads();
    float bias = b_n2[j];
    float acc[8];
#pragma unroll
    for (int b = 0; b < 8; ++b) acc[b] = bias;
    for (int k4 = 0; k4 < HDIM / 4; ++k4) {
        float w0 = W_n2[(size_t)(k4 * 4 + 0) * NOUT + j];
        float w1 = W_n2[(size_t)(k4 * 4 + 1) * NOUT + j];
        float w2 = W_n2[(size_t)(k4 * 4 + 2) * NOUT + j];
        float w3 = W_n2[(size_t)(k4 * 4 + 3) * NOUT + j];
#pragma unroll
        for (int b = 0; b < 8; ++b) {
            float4 nv = *reinterpret_cast<const float4*>(&s[b * HDIM + k4 * 4]);
            acc[b] += nv.x * w0 + nv.y * w1 + nv.z * w2 + nv.w * w3;
        }
    }
#pragma unroll
    for (int b = 0; b < 8; ++b)
        out_nl[(size_t)(bg * 8 + b) * NOUT + j] = acc[b];
}

// ============ k_edge: per (batch, r-quarter); produce then consume =========
// grid (256,4), block 256, LDS 25.6KB. __launch_bounds__(256,4) caps VGPR at
// 128 -> 16 waves/CU -> exactly 4 blocks/CU, grid = one full pass.
__global__ __launch_bounds__(256, 4) void k_edge(
        const float* __restrict__ nl,    // [256,50,32]
        const float* __restrict__ u,     // [256,512]
        const float* __restrict__ pW1,   // [50,512]
        const float* __restrict__ W_e1,  // [576,512]
        const float* __restrict__ b_e1,  // [512]
        const float* __restrict__ W_e2,  // [512,5]
        float* __restrict__ P) {         // [4][256][1225][5]
    int b  = blockIdx.x;
    int rh = blockIdx.y;
    int t  = threadIdx.x;
    int rbase = rh * 128;

    __shared__ float As[NDIM * CH];   // 12.8 KB
    __shared__ float Bs[NDIM * CH];   // 12.8 KB

    // task decode: (p,q): rows i0=2p,i0+1; cols j0=3q..3q+2; 225 valid tiles
    bool has = (t < 225);
    int pp = 0, qq = 0;
    if (has) {
        int tt = t;
        for (pp = 0; pp < 25; ++pp) {
            int qmin = pp ? ((2 * pp - 2) / 3 + 1) : 0;
            int cnt = 17 - qmin;
            if (tt < cnt) { qq = qmin + tt; break; }
            tt -= cnt;
        }
    }
    int i0 = 2 * pp, i1 = i0 + 1;
    int j0 = 3 * qq, j1 = j0 + 1, j2r = (3 * qq + 2 < NDIM) ? 3 * qq + 2 : NDIM - 1;

    float acc[6][EOUT];
#pragma unroll
    for (int e = 0; e < 6; ++e)
#pragma unroll
        for (int o = 0; o < EOUT; ++o) acc[e][o] = 0.f;

    // produce role: c = t&63, arr = (t>>6)&1, nh = t>>7 (25 rows each)
    int c = t & 63, arr = (t >> 6) & 1, nh = t >> 7;
    const float4* nl4 = reinterpret_cast<const float4*>(nl + (size_t)b * (NDIM * DDIM));

    for (int ch = 0; ch < 2; ++ch) {
        int col = rbase + ch * CH + c;
        // ---- produce ----
        {
            float w[DDIM];
#pragma unroll
            for (int k = 0; k < DDIM; ++k)
                w[k] = W_e1[(size_t)(HDIM + arr * DDIM + k) * HDIM + col];
            float cm = 0.5f * (u[(size_t)b * HDIM + col] + b_e1[col]);
            float* dst = arr ? Bs : As;
            int n0 = nh * 25;
            for (int k = 0; k < 25; ++k) {
                int n = n0 + k;
                float a = cm + pW1[(size_t)n * HDIM + col];
#pragma unroll
                for (int q8 = 0; q8 < 8; ++q8) {
                    float4 x = nl4[n * 8 + q8];   // wave-uniform -> s_load
                    a += x.x * w[4*q8] + x.y * w[4*q8+1] + x.z * w[4*q8+2] + x.w * w[4*q8+3];
                }
                dst[n * CH + ((((c >> 2) ^ (n & 7)) << 2) | (c & 3))] = a;
            }
        }
        __syncthreads();
        // ---- consume ----
        if (has) {
            const float4* A4 = reinterpret_cast<const float4*>(As);
            const float4* B4 = reinterpret_cast<const float4*>(Bs);
            const float* wch = W_e2 + (size_t)(rbase + ch * CH) * EOUT;
            for (int r4 = 0; r4 < CH / 4; ++r4) {
                const float* wr = wch + r4 * 4 * EOUT;   // uniform -> s_load
                float4 a0 = A4[i0 * 16 + (r4 ^ (i0 & 7))];
                float4 a1 = A4[i1 * 16 + (r4 ^ (i1 & 7))];
                float4 b0 = B4[j0 * 16 + (r4 ^ (j0 & 7))];
                float4 b1 = B4[j1 * 16 + (r4 ^ (j1 & 7))];
                float4 b2 = B4[j2r * 16 + (r4 ^ (j2r & 7))];
#pragma unroll
                for (int rr = 0; rr < 4; ++rr) {
                    float av0 = (&a0.x)[rr], av1 = (&a1.x)[rr];
                    float bv0 = (&b0.x)[rr], bv1 = (&b1.x)[rr], bv2 = (&b2.x)[rr];
                    float v0 = fmaxf(av0 + bv0, 0.f);
                    float v1 = fmaxf(av0 + bv1, 0.f);
                    float v2 = fmaxf(av0 + bv2, 0.f);
                    float v3 = fmaxf(av1 + bv0, 0.f);
                    float v4 = fmaxf(av1 + bv1, 0.f);
                    float v5 = fmaxf(av1 + bv2, 0.f);
#pragma unroll
                    for (int o = 0; o < EOUT; ++o) {
                        float wv = wr[rr * EOUT + o];
                        acc[0][o] += v0 * wv;
                        acc[1][o] += v1 * wv;
                        acc[2][o] += v2 * wv;
                        acc[3][o] += v3 * wv;
                        acc[4][o] += v4 * wv;
                        acc[5][o] += v5 * wv;
                    }
                }
            }
        }
        __syncthreads();
    }

    if (has) {
        float* Pb = P + ((size_t)rh * BSZ + b) * NEDGE * EOUT;
        int js[3] = {j0, j1, 3 * qq + 2};
#pragma unroll
        for (int r = 0; r < 2; ++r) {
            int i = i0 + r;
#pragma unroll
            for (int cc = 0; cc < 3; ++cc) {
                int j = js[cc];
                if (i < j && j < NDIM) {
                    int e = i * (NDIM - 1) - (i * (i - 1)) / 2 + (j - i - 1);
#pragma unroll
                    for (int o = 0; o < EOUT; ++o)
                        Pb[(size_t)e * EOUT + o] = acc[r * 3 + cc][o];
                }
            }
        }
    }
}

// ============ k_comb: out_el = P0+P1+P2+P3 + bias (float4 x5/thread) =======
__global__ __launch_bounds__(256) void k_comb(const float* __restrict__ P,
                                              const float* __restrict__ b_e2,
                                              float* __restrict__ out_el,
                                              float* __restrict__ out_idx) {
    int blk = blockIdx.x, t = threadIdx.x;
    const size_t PS = (size_t)BSZ * NEDGE * EOUT;
    if (blk < 307) {
        int tid = blk * 256 + t;       // 20 floats per thread; 78400 total
        if (tid < 78400) {
            const float4* p0 = reinterpret_cast<const float4*>(P) + (size_t)tid * 5;
            const float4* p1 = reinterpret_cast<const float4*>(P + PS) + (size_t)tid * 5;
            const float4* p2 = reinterpret_cast<const float4*>(P + 2 * PS) + (size_t)tid * 5;
            const float4* p3 = reinterpret_cast<const float4*>(P + 3 * PS) + (size_t)tid * 5;
            float4* o = reinterpret_cast<float4*>(out_el) + (size_t)tid * 5;
            float b5[5];
#pragma unroll
            for (int cc = 0; cc < 5; ++cc) b5[cc] = b_e2[cc];
#pragma unroll
            for (int q = 0; q < 5; ++q) {
                float4 a = p0[q], b = p1[q], cq = p2[q], d = p3[q];
                float4 r;
                r.x = a.x + b.x + cq.x + d.x + b5[(q * 4 + 0) % 5];
                r.y = a.y + b.y + cq.y + d.y + b5[(q * 4 + 1) % 5];
                r.z = a.z + b.z + cq.z + d.z + b5[(q * 4 + 2) % 5];
                r.w = a.w + b.w + cq.w + d.w + b5[(q * 4 + 3) % 5];
                o[q] = r;
            }
        }
    } else {
        int e = (blk - 307) * 256 + t;
        if (e < NEDGE) {
            int i = 0, rem = e;
            while (rem >= (NDIM - 1 - i)) { rem -= (NDIM - 1 - i); ++i; }
            int j = i + 1 + rem;
            out_idx[e * 2] = (float)i;
            out_idx[e * 2 + 1] = (float)j;
        }
    }
}

extern "C" void kernel_launch(void* const* d_in, const int* in_sizes, int n_in,
                              void* d_out, int out_size, void* d_ws, size_t ws_size,
                              hipStream_t stream) {
    const float* z    = (const float*)d_in[0];
    const float* tp   = (const float*)d_in[1];
    const float* W_in = (const float*)d_in[2];
    const float* b_in = (const float*)d_in[3];
    const float* W_s1 = (const float*)d_in[4];
    const float* b_s1 = (const float*)d_in[5];
    const float* W_s2 = (const float*)d_in[6];
    const float* b_s2 = (const float*)d_in[7];
    const float* W_n1 = (const float*)d_in[8];
    const float* b_n1 = (const float*)d_in[9];
    const float* W_n2 = (const float*)d_in[10];
    const float* b_n2 = (const float*)d_in[11];
    const float* W_e1 = (const float*)d_in[12];
    const float* b_e1 = (const float*)d_in[13];
    const float* W_e2 = (const float*)d_in[14];
    const float* b_e2 = (const float*)d_in[15];
    const float* pe   = (const float*)d_in[16];

    float* out     = (float*)d_out;
    float* out_nl  = out;                 // node_logits
    float* out_el  = out + 409600;        // edge_logits
    float* out_sp  = out + 1977600;       // size_probs
    float* out_idx = out + 1990400;       // edge_indices (as float)

    float* ws  = (float*)d_ws;
    float* u   = ws;
    float* pW1 = ws + 131072;
    float* n1  = ws + 156672;
    float* P   = ws + 287744;             // [4][256][1225][5]

    k_pre<<<333, 512, 0, stream>>>(z, tp, W_in, b_in, W_s1, b_s1, W_s2, b_s2,
                                   W_n1, b_n1, W_e1, pe, n1, u, pW1, out_sp);
    k_nl<<<dim3(32, 5), 320, 0, stream>>>(n1, W_n2, b_n2, out_nl);
    k_edge<<<dim3(BSZ, NRH), 256, 0, stream>>>(out_nl, u, pW1, W_e1, b_e1, W_e2, P);
    k_comb<<<312, 256, 0, stream>>>(P, b_e2, out_el, out_idx);
}

// Round 9
// 232.339 us; speedup vs baseline: 1.2625x; 1.2625x over previous
//
#include <hip/hip_runtime.h>
#include <math.h>

// Problem dims
#define BSZ   256
#define LDIM  128
#define PDIM  3
#define HDIM  512
#define DDIM  32
#define NDIM  50
#define NEDGE 1225   // N*(N-1)/2
#define EOUT  5      // EDIM+1
#define CH    128    // edge chunk cols
#define NRH   2      // r-splits

// out layout (floats)
//   node_logits  [256,50,32]   @ 0        (409600)
//   edge_logits  [256,1225,5]  @ 409600   (1568000)
//   size_probs   [256,50]      @ 1977600  (12800)
//   edge_indices [1225,2]      @ 1990400  (2450, float values)
// ws layout (floats): u @0 (131072), pW1 @131072 (25600), n1 @156672 (131072),
//                     P @287744 (2 x 1568000)

// ============ k_pre: roles {h->n1 (2b), h->u (2b), h->size (4b), pW1} =====
__global__ __launch_bounds__(512) void k_pre(
        const float* __restrict__ z, const float* __restrict__ tp,
        const float* __restrict__ W_in, const float* __restrict__ b_in,
        const float* __restrict__ W_s1, const float* __restrict__ b_s1,
        const float* __restrict__ W_s2, const float* __restrict__ b_s2,
        const float* __restrict__ W_n1, const float* __restrict__ b_n1,
        const float* __restrict__ W_e1, const float* __restrict__ pe,
        float* __restrict__ n1, float* __restrict__ u,
        float* __restrict__ pW1, float* __restrict__ out_sp) {
    int bx = blockIdx.x, t = threadIdx.x;
    __shared__ float sA[4][HDIM];
    __shared__ float sB[4][HDIM];

    if (bx < 256) {
        int role = bx >> 7;            // 0: n1, 1: u
        int b0 = (bx & 127) * 2;
        float* sin_ = &sB[0][0];       // 262 floats
        for (int idx = t; idx < 2 * 131; idx += 512) {
            int bi = idx / 131, k = idx % 131;
            sin_[idx] = (k < LDIM) ? z[(size_t)(b0 + bi) * LDIM + k]
                                   : tp[(size_t)(b0 + bi) * PDIM + (k - LDIM)];
        }
        __syncthreads();
        {
            float bin = b_in[t];
            float a0 = bin, a1 = bin;
            for (int k = 0; k < LDIM + PDIM; ++k) {
                float w = W_in[(size_t)k * HDIM + t];
                a0 += sin_[k] * w;
                a1 += sin_[131 + k] * w;
            }
            sA[0][t] = fmaxf(a0, 0.f);
            sA[1][t] = fmaxf(a1, 0.f);
        }
        __syncthreads();
        const float* W = (role == 0) ? W_n1 : W_e1;   // W1h = rows 0..511 of W_e1
        float a0 = 0.f, a1 = 0.f;
        for (int k4 = 0; k4 < HDIM / 4; ++k4) {
            float w0 = W[(size_t)(k4 * 4 + 0) * HDIM + t];
            float w1 = W[(size_t)(k4 * 4 + 1) * HDIM + t];
            float w2 = W[(size_t)(k4 * 4 + 2) * HDIM + t];
            float w3 = W[(size_t)(k4 * 4 + 3) * HDIM + t];
            float4 x0 = *reinterpret_cast<const float4*>(&sA[0][k4 * 4]);
            float4 x1 = *reinterpret_cast<const float4*>(&sA[1][k4 * 4]);
            a0 += x0.x * w0 + x0.y * w1 + x0.z * w2 + x0.w * w3;
            a1 += x1.x * w0 + x1.y * w1 + x1.z * w2 + x1.w * w3;
        }
        if (role == 0) {
            float bb = b_n1[t];
            n1[(size_t)(b0 + 0) * HDIM + t] = fmaxf(a0 + bb, 0.f);
            n1[(size_t)(b0 + 1) * HDIM + t] = fmaxf(a1 + bb, 0.f);
        } else {
            u[(size_t)(b0 + 0) * HDIM + t] = a0;
            u[(size_t)(b0 + 1) * HDIM + t] = a1;
        }
    } else if (bx < 320) {
        // ---- role size head: 4 batches ------------------------------------
        int b0 = (bx - 256) * 4;
        float* sin_ = &sB[0][0];       // 524 floats
        for (int idx = t; idx < 4 * 131; idx += 512) {
            int bi = idx / 131, k = idx % 131;
            sin_[idx] = (k < LDIM) ? z[(size_t)(b0 + bi) * LDIM + k]
                                   : tp[(size_t)(b0 + bi) * PDIM + (k - LDIM)];
        }
        __syncthreads();
        {
            float bin = b_in[t];
            float a0 = bin, a1 = bin, a2 = bin, a3 = bin;
            for (int k = 0; k < LDIM + PDIM; ++k) {
                float w = W_in[(size_t)k * HDIM + t];
                a0 += sin_[0 * 131 + k] * w;
                a1 += sin_[1 * 131 + k] * w;
                a2 += sin_[2 * 131 + k] * w;
                a3 += sin_[3 * 131 + k] * w;
            }
            sA[0][t] = fmaxf(a0, 0.f); sA[1][t] = fmaxf(a1, 0.f);
            sA[2][t] = fmaxf(a2, 0.f); sA[3][t] = fmaxf(a3, 0.f);
        }
        __syncthreads();
        float* s1b = &sB[0][0];    // [4][256]
        float* slg = &sB[2][0];    // [4][50]
        {
            int c = t & 255, bp = t >> 8;   // batches 2bp, 2bp+1
            float bv = b_s1[c];
            float a0 = bv, a1 = bv;
            for (int k = 0; k < HDIM; ++k) {
                float w = W_s1[(size_t)k * (HDIM / 2) + c];
                a0 += sA[2 * bp][k] * w;
                a1 += sA[2 * bp + 1][k] * w;
            }
            __syncthreads();
            s1b[(2 * bp) * 256 + c] = fmaxf(a0, 0.f);
            s1b[(2 * bp + 1) * 256 + c] = fmaxf(a1, 0.f);
        }
        __syncthreads();
        int b4 = t / NDIM, o = t % NDIM;
        if (t < 4 * NDIM) {
            float a = b_s2[o];
            for (int k = 0; k < HDIM / 2; ++k)
                a += s1b[b4 * 256 + k] * W_s2[(size_t)k * NDIM + o];
            slg[b4 * NDIM + o] = a;
        }
        __syncthreads();
        if (t < 4 * NDIM) {
            float m = slg[b4 * NDIM];
            for (int k = 1; k < NDIM; ++k) m = fmaxf(m, slg[b4 * NDIM + k]);
            float s = 0.f;
            for (int k = 0; k < NDIM; ++k) s += expf(slg[b4 * NDIM + k] - m);
            out_sp[(size_t)(b0 + b4) * NDIM + o] = expf(slg[b4 * NDIM + o] - m) / s;
        }
    } else {
        // ---- role pW1: 0.5 * pe @ W1h, 4 rows -----------------------------
        int r0 = (bx - 320) * 4;
        int r[4];
#pragma unroll
        for (int q = 0; q < 4; ++q) { int rr = r0 + q; r[q] = (rr < NDIM) ? rr : NDIM - 1; }
        for (int idx = t; idx < 4 * HDIM; idx += 512)
            sA[idx >> 9][idx & 511] = pe[(size_t)r[idx >> 9] * HDIM + (idx & 511)];
        __syncthreads();
        float a0 = 0.f, a1 = 0.f, a2 = 0.f, a3 = 0.f;
        for (int k4 = 0; k4 < HDIM / 4; ++k4) {
            float w0 = W_e1[(size_t)(k4 * 4 + 0) * HDIM + t];
            float w1 = W_e1[(size_t)(k4 * 4 + 1) * HDIM + t];
            float w2 = W_e1[(size_t)(k4 * 4 + 2) * HDIM + t];
            float w3 = W_e1[(size_t)(k4 * 4 + 3) * HDIM + t];
            float4 x0 = *reinterpret_cast<const float4*>(&sA[0][k4 * 4]);
            float4 x1 = *reinterpret_cast<const float4*>(&sA[1][k4 * 4]);
            float4 x2 = *reinterpret_cast<const float4*>(&sA[2][k4 * 4]);
            float4 x3 = *reinterpret_cast<const float4*>(&sA[3][k4 * 4]);
            a0 += x0.x * w0 + x0.y * w1 + x0.z * w2 + x0.w * w3;
            a1 += x1.x * w0 + x1.y * w1 + x1.z * w2 + x1.w * w3;
            a2 += x2.x * w0 + x2.y * w1 + x2.z * w2 + x2.w * w3;
            a3 += x3.x * w0 + x3.y * w1 + x3.z * w2 + x3.w * w3;
        }
        pW1[(size_t)r[0] * HDIM + t] = 0.5f * a0;
        pW1[(size_t)r[1] * HDIM + t] = 0.5f * a1;
        pW1[(size_t)r[2] * HDIM + t] = 0.5f * a2;
        pW1[(size_t)r[3] * HDIM + t] = 0.5f * a3;
    }
}

// ============ k_nl: [256,512]@[512,1600]+b, 8 batches/block ================
__global__ __launch_bounds__(320) void k_nl(const float* __restrict__ n1,
                                            const float* __restrict__ W_n2,
                                            const float* __restrict__ b_n2,
                                            float* __restrict__ out_nl) {
    const int NOUT = NDIM * DDIM;   // 1600
    int t = threadIdx.x;
    int j = blockIdx.y * 320 + t;
    int bg = blockIdx.x;            // 8 batches
    __shared__ float s[8 * HDIM];
    for (int idx = t; idx < 8 * HDIM / 4; idx += 320) {
        int lin = idx * 4;
        int row = lin >> 9, col = lin & 511;
        *reinterpret_cast<float4*>(&s[row * HDIM + col]) =
            *reinterpret_cast<const float4*>(&n1[(size_t)(bg * 8 + row) * HDIM + col]);
    }
    __syncthreads();
    float bias = b_n2[j];
    float acc[8];
#pragma unroll
    for (int b = 0; b < 8; ++b) acc[b] = bias;
    for (int k4 = 0; k4 < HDIM / 4; ++k4) {
        float w0 = W_n2[(size_t)(k4 * 4 + 0) * NOUT + j];
        float w1 = W_n2[(size_t)(k4 * 4 + 1) * NOUT + j];
        float w2 = W_n2[(size_t)(k4 * 4 + 2) * NOUT + j];
        float w3 = W_n2[(size_t)(k4 * 4 + 3) * NOUT + j];
#pragma unroll
        for (int b = 0; b < 8; ++b) {
            float4 nv = *reinterpret_cast<const float4*>(&s[b * HDIM + k4 * 4]);
            acc[b] += nv.x * w0 + nv.y * w1 + nv.z * w2 + nv.w * w3;
        }
    }
#pragma unroll
    for (int b = 0; b < 8; ++b)
        out_nl[(size_t)(bg * 8 + b) * NOUT + j] = acc[b];
}

// ============ k_edge: 512 threads, per (batch, r-half) =====================
// grid (256,2) = 512 blocks -> 2 blocks/CU = 16 waves/CU.
// Produce: 512 threads = 2 n-halves x 2 arrays x 128 cols, 25 rows each.
// Consume: 425 tasks of 1x3 j-tiles, acc[3][5] = 15 regs.
__global__ __launch_bounds__(512) void k_edge(
        const float* __restrict__ nl,    // [256,50,32]
        const float* __restrict__ u,     // [256,512]
        const float* __restrict__ pW1,   // [50,512]
        const float* __restrict__ W_e1,  // [576,512]
        const float* __restrict__ b_e1,  // [512]
        const float* __restrict__ W_e2,  // [512,5]
        float* __restrict__ P) {         // [2][256][1225][5]
    int b  = blockIdx.x;
    int rh = blockIdx.y;
    int t  = threadIdx.x;
    int rbase = rh * 256;

    __shared__ float As[NDIM * CH];   // 25.6 KB
    __shared__ float Bs[NDIM * CH];   // 25.6 KB

    // consume task decode: 1x3 j-tiles, 425 tasks
    bool has = (t < 425);
    int ti = 0, j0 = 1;
    if (has) {
        int rem = t, i = 0;
        while (rem >= (NDIM - 1 - i + 2) / 3) { rem -= (NDIM - 1 - i + 2) / 3; ++i; }
        ti = i; j0 = i + 1 + 3 * rem;
    }
    bool ok1 = has && (j0 + 1 < NDIM);
    bool ok2 = has && (j0 + 2 < NDIM);
    int j1c = (j0 + 1 < NDIM) ? j0 + 1 : NDIM - 1;
    int j2c = (j0 + 2 < NDIM) ? j0 + 2 : NDIM - 1;

    float acc0[EOUT] = {0.f, 0.f, 0.f, 0.f, 0.f};
    float acc1[EOUT] = {0.f, 0.f, 0.f, 0.f, 0.f};
    float acc2[EOUT] = {0.f, 0.f, 0.f, 0.f, 0.f};

    // produce role: c = t&127, arr = (t>>7)&1, nh = t>>8 (25 rows each)
    int c = t & 127, arr = (t >> 7) & 1, nh = t >> 8;
    const float4* nl4 = reinterpret_cast<const float4*>(nl + (size_t)b * (NDIM * DDIM));

    for (int ch = 0; ch < 2; ++ch) {
        int col = rbase + ch * CH + c;
        // ---- produce ----
        {
            float w[DDIM];
#pragma unroll
            for (int k = 0; k < DDIM; ++k)
                w[k] = W_e1[(size_t)(HDIM + arr * DDIM + k) * HDIM + col];
            float cm = 0.5f * (u[(size_t)b * HDIM + col] + b_e1[col]);
            float* dst = arr ? Bs : As;
            int n0 = nh * 25;
            for (int k = 0; k < 25; ++k) {
                int n = n0 + k;
                float a = cm + pW1[(size_t)n * HDIM + col];
#pragma unroll
                for (int q8 = 0; q8 < 8; ++q8) {
                    float4 x = nl4[n * 8 + q8];   // wave-uniform -> s_load
                    a += x.x * w[4*q8] + x.y * w[4*q8+1] + x.z * w[4*q8+2] + x.w * w[4*q8+3];
                }
                dst[n * CH + ((((c >> 2) ^ (n & 7)) << 2) | (c & 3))] = a;
            }
        }
        __syncthreads();
        // ---- consume ----
        if (has) {
            const float4* A4 = reinterpret_cast<const float4*>(As);
            const float4* B4 = reinterpret_cast<const float4*>(Bs);
            const float* wch = W_e2 + (size_t)(rbase + ch * CH) * EOUT;
            for (int r4 = 0; r4 < CH / 4; ++r4) {
                const float* wr = wch + r4 * 4 * EOUT;   // uniform -> s_load
                float4 av = A4[ti * 32 + (r4 ^ (ti & 7))];
                float4 b0 = B4[j0 * 32 + (r4 ^ (j0 & 7))];
                float4 b1 = B4[j1c * 32 + (r4 ^ (j1c & 7))];
                float4 b2 = B4[j2c * 32 + (r4 ^ (j2c & 7))];
#pragma unroll
                for (int rr = 0; rr < 4; ++rr) {
                    float a = (&av.x)[rr];
                    float v0 = fmaxf(a + (&b0.x)[rr], 0.f);
                    float v1 = fmaxf(a + (&b1.x)[rr], 0.f);
                    float v2 = fmaxf(a + (&b2.x)[rr], 0.f);
#pragma unroll
                    for (int o = 0; o < EOUT; ++o) {
                        float wv = wr[rr * EOUT + o];
                        acc0[o] += v0 * wv;
                        acc1[o] += v1 * wv;
                        acc2[o] += v2 * wv;
                    }
                }
            }
        }
        __syncthreads();
    }

    if (has) {
        int e0 = ti * (NDIM - 1) - (ti * (ti - 1)) / 2 + (j0 - ti - 1);
        float* Pb = P + ((size_t)rh * BSZ + b) * NEDGE * EOUT + (size_t)e0 * EOUT;
#pragma unroll
        for (int o = 0; o < EOUT; ++o) Pb[o] = acc0[o];
        if (ok1) {
#pragma unroll
            for (int o = 0; o < EOUT; ++o) Pb[EOUT + o] = acc1[o];
        }
        if (ok2) {
#pragma unroll
            for (int o = 0; o < EOUT; ++o) Pb[2 * EOUT + o] = acc2[o];
        }
    }
}

// ============ k_comb: out_el = P0+P1 + bias (float4 x5/thread) =============
__global__ __launch_bounds__(256) void k_comb(const float* __restrict__ P,
                                              const float* __restrict__ b_e2,
                                              float* __restrict__ out_el,
                                              float* __restrict__ out_idx) {
    int blk = blockIdx.x, t = threadIdx.x;
    const size_t PS = (size_t)BSZ * NEDGE * EOUT;
    if (blk < 307) {
        int tid = blk * 256 + t;       // 20 floats per thread; 78400 total
        if (tid < 78400) {
            const float4* p0 = reinterpret_cast<const float4*>(P) + (size_t)tid * 5;
            const float4* p1 = reinterpret_cast<const float4*>(P + PS) + (size_t)tid * 5;
            float4* o = reinterpret_cast<float4*>(out_el) + (size_t)tid * 5;
            float b5[5];
#pragma unroll
            for (int cc = 0; cc < 5; ++cc) b5[cc] = b_e2[cc];
#pragma unroll
            for (int q = 0; q < 5; ++q) {
                float4 a = p0[q], b = p1[q];
                float4 r;
                r.x = a.x + b.x + b5[(q * 4 + 0) % 5];
                r.y = a.y + b.y + b5[(q * 4 + 1) % 5];
                r.z = a.z + b.z + b5[(q * 4 + 2) % 5];
                r.w = a.w + b.w + b5[(q * 4 + 3) % 5];
                o[q] = r;
            }
        }
    } else {
        int e = (blk - 307) * 256 + t;
        if (e < NEDGE) {
            int i = 0, rem = e;
            while (rem >= (NDIM - 1 - i)) { rem -= (NDIM - 1 - i); ++i; }
            int j = i + 1 + rem;
            out_idx[e * 2] = (float)i;
            out_idx[e * 2 + 1] = (float)j;
        }
    }
}

extern "C" void kernel_launch(void* const* d_in, const int* in_sizes, int n_in,
                              void* d_out, int out_size, void* d_ws, size_t ws_size,
                              hipStream_t stream) {
    const float* z    = (const float*)d_in[0];
    const float* tp   = (const float*)d_in[1];
    const float* W_in = (const float*)d_in[2];
    const float* b_in = (const float*)d_in[3];
    const float* W_s1 = (const float*)d_in[4];
    const float* b_s1 = (const float*)d_in[5];
    const float* W_s2 = (const float*)d_in[6];
    const float* b_s2 = (const float*)d_in[7];
    const float* W_n1 = (const float*)d_in[8];
    const float* b_n1 = (const float*)d_in[9];
    const float* W_n2 = (const float*)d_in[10];
    const float* b_n2 = (const float*)d_in[11];
    const float* W_e1 = (const float*)d_in[12];
    const float* b_e1 = (const float*)d_in[13];
    const float* W_e2 = (const float*)d_in[14];
    const float* b_e2 = (const float*)d_in[15];
    const float* pe   = (const float*)d_in[16];

    float* out     = (float*)d_out;
    float* out_nl  = out;                 // node_logits
    float* out_el  = out + 409600;        // edge_logits
    float* out_sp  = out + 1977600;       // size_probs
    float* out_idx = out + 1990400;       // edge_indices (as float)

    float* ws  = (float*)d_ws;
    float* u   = ws;
    float* pW1 = ws + 131072;
    float* n1  = ws + 156672;
    float* P   = ws + 287744;             // [2][256][1225][5]

    k_pre<<<333, 512, 0, stream>>>(z, tp, W_in, b_in, W_s1, b_s1, W_s2, b_s2,
                                   W_n1, b_n1, W_e1, pe, n1, u, pW1, out_sp);
    k_nl<<<dim3(32, 5), 320, 0, stream>>>(n1, W_n2, b_n2, out_nl);
    k_edge<<<dim3(BSZ, NRH), 512, 0, stream>>>(out_nl, u, pW1, W_e1, b_e1, W_e2, P);
    k_comb<<<312, 256, 0, stream>>>(P, b_e2, out_el, out_idx);
}

// Round 10
// 185.585 us; speedup vs baseline: 1.5805x; 1.2519x over previous
//
#include <hip/hip_runtime.h>
#include <math.h>

// Problem dims
#define BSZ   256
#define LDIM  128
#define PDIM  3
#define HDIM  512
#define DDIM  32
#define NDIM  50
#define NEDGE 1225   // N*(N-1)/2
#define EOUT  5      // EDIM+1
#define CH    64     // edge chunk cols (round-6 value; 2 chunks per r-half)
#define NRH   4      // r-splits? NO -> round 6 used NRH=2 with CH=128. See below.

// NOTE: k_edge below is the round-6 structure: grid (256,2), block 256,
// r-half of 256 cols processed as 2 chunks of 128; LDS 2x25.6KB.
#define ECH   128    // cols per chunk in k_edge

// out layout (floats)
//   node_logits  [256,50,32]   @ 0        (409600)
//   edge_logits  [256,1225,5]  @ 409600   (1568000)
//   size_probs   [256,50]      @ 1977600  (12800)
//   edge_indices [1225,2]      @ 1990400  (2450, float values)
// ws layout (floats): u @0 (131072), pW1 @131072 (25600), n1 @156672 (131072),
//                     P @287744 (2 x 1568000)

// ============ k_pre: roles {h->n1 (2b), h->u (2b), h->size (4b), pW1} =====
__global__ __launch_bounds__(512) void k_pre(
        const float* __restrict__ z, const float* __restrict__ tp,
        const float* __restrict__ W_in, const float* __restrict__ b_in,
        const float* __restrict__ W_s1, const float* __restrict__ b_s1,
        const float* __restrict__ W_s2, const float* __restrict__ b_s2,
        const float* __restrict__ W_n1, const float* __restrict__ b_n1,
        const float* __restrict__ W_e1, const float* __restrict__ pe,
        float* __restrict__ n1, float* __restrict__ u,
        float* __restrict__ pW1, float* __restrict__ out_sp) {
    int bx = blockIdx.x, t = threadIdx.x;
    __shared__ float sA[4][HDIM];
    __shared__ float sB[4][HDIM];

    if (bx < 256) {
        int role = bx >> 7;            // 0: n1, 1: u
        int b0 = (bx & 127) * 2;
        float* sin_ = &sB[0][0];       // 262 floats
        for (int idx = t; idx < 2 * 131; idx += 512) {
            int bi = idx / 131, k = idx % 131;
            sin_[idx] = (k < LDIM) ? z[(size_t)(b0 + bi) * LDIM + k]
                                   : tp[(size_t)(b0 + bi) * PDIM + (k - LDIM)];
        }
        __syncthreads();
        {
            float bin = b_in[t];
            float a0 = bin, a1 = bin;
            for (int k = 0; k < LDIM + PDIM; ++k) {
                float w = W_in[(size_t)k * HDIM + t];
                a0 += sin_[k] * w;
                a1 += sin_[131 + k] * w;
            }
            sA[0][t] = fmaxf(a0, 0.f);
            sA[1][t] = fmaxf(a1, 0.f);
        }
        __syncthreads();
        const float* W = (role == 0) ? W_n1 : W_e1;   // W1h = rows 0..511 of W_e1
        // 4 independent chains (2 per batch) to break fp32 dep chains
        float s0a = 0.f, s0b = 0.f, s1a = 0.f, s1b = 0.f;
        for (int k4 = 0; k4 < HDIM / 4; ++k4) {
            float w0 = W[(size_t)(k4 * 4 + 0) * HDIM + t];
            float w1 = W[(size_t)(k4 * 4 + 1) * HDIM + t];
            float w2 = W[(size_t)(k4 * 4 + 2) * HDIM + t];
            float w3 = W[(size_t)(k4 * 4 + 3) * HDIM + t];
            float4 x0 = *reinterpret_cast<const float4*>(&sA[0][k4 * 4]);
            float4 x1 = *reinterpret_cast<const float4*>(&sA[1][k4 * 4]);
            s0a += x0.x * w0 + x0.y * w1;
            s0b += x0.z * w2 + x0.w * w3;
            s1a += x1.x * w0 + x1.y * w1;
            s1b += x1.z * w2 + x1.w * w3;
        }
        float a0 = s0a + s0b, a1 = s1a + s1b;
        if (role == 0) {
            float bb = b_n1[t];
            n1[(size_t)(b0 + 0) * HDIM + t] = fmaxf(a0 + bb, 0.f);
            n1[(size_t)(b0 + 1) * HDIM + t] = fmaxf(a1 + bb, 0.f);
        } else {
            u[(size_t)(b0 + 0) * HDIM + t] = a0;
            u[(size_t)(b0 + 1) * HDIM + t] = a1;
        }
    } else if (bx < 320) {
        // ---- role size head: 4 batches ------------------------------------
        int b0 = (bx - 256) * 4;
        float* sin_ = &sB[0][0];       // 524 floats
        for (int idx = t; idx < 4 * 131; idx += 512) {
            int bi = idx / 131, k = idx % 131;
            sin_[idx] = (k < LDIM) ? z[(size_t)(b0 + bi) * LDIM + k]
                                   : tp[(size_t)(b0 + bi) * PDIM + (k - LDIM)];
        }
        __syncthreads();
        {
            float bin = b_in[t];
            float a0 = bin, a1 = bin, a2 = bin, a3 = bin;
            for (int k = 0; k < LDIM + PDIM; ++k) {
                float w = W_in[(size_t)k * HDIM + t];
                a0 += sin_[0 * 131 + k] * w;
                a1 += sin_[1 * 131 + k] * w;
                a2 += sin_[2 * 131 + k] * w;
                a3 += sin_[3 * 131 + k] * w;
            }
            sA[0][t] = fmaxf(a0, 0.f); sA[1][t] = fmaxf(a1, 0.f);
            sA[2][t] = fmaxf(a2, 0.f); sA[3][t] = fmaxf(a3, 0.f);
        }
        __syncthreads();
        float* s1b = &sB[0][0];    // [4][256]
        float* slg = &sB[2][0];    // [4][50]
        {
            int c = t & 255, bp = t >> 8;   // batches 2bp, 2bp+1
            float bv = b_s1[c];
            float a0 = bv, a1 = bv;
            for (int k = 0; k < HDIM; ++k) {
                float w = W_s1[(size_t)k * (HDIM / 2) + c];
                a0 += sA[2 * bp][k] * w;
                a1 += sA[2 * bp + 1][k] * w;
            }
            __syncthreads();
            s1b[(2 * bp) * 256 + c] = fmaxf(a0, 0.f);
            s1b[(2 * bp + 1) * 256 + c] = fmaxf(a1, 0.f);
        }
        __syncthreads();
        int b4 = t / NDIM, o = t % NDIM;
        if (t < 4 * NDIM) {
            float a = b_s2[o];
            for (int k = 0; k < HDIM / 2; ++k)
                a += s1b[b4 * 256 + k] * W_s2[(size_t)k * NDIM + o];
            slg[b4 * NDIM + o] = a;
        }
        __syncthreads();
        if (t < 4 * NDIM) {
            float m = slg[b4 * NDIM];
            for (int k = 1; k < NDIM; ++k) m = fmaxf(m, slg[b4 * NDIM + k]);
            float s = 0.f;
            for (int k = 0; k < NDIM; ++k) s += expf(slg[b4 * NDIM + k] - m);
            out_sp[(size_t)(b0 + b4) * NDIM + o] = expf(slg[b4 * NDIM + o] - m) / s;
        }
    } else {
        // ---- role pW1: 0.5 * pe @ W1h, 4 rows -----------------------------
        int r0 = (bx - 320) * 4;
        int r[4];
#pragma unroll
        for (int q = 0; q < 4; ++q) { int rr = r0 + q; r[q] = (rr < NDIM) ? rr : NDIM - 1; }
        for (int idx = t; idx < 4 * HDIM; idx += 512)
            sA[idx >> 9][idx & 511] = pe[(size_t)r[idx >> 9] * HDIM + (idx & 511)];
        __syncthreads();
        float a0 = 0.f, a1 = 0.f, a2 = 0.f, a3 = 0.f;
        for (int k4 = 0; k4 < HDIM / 4; ++k4) {
            float w0 = W_e1[(size_t)(k4 * 4 + 0) * HDIM + t];
            float w1 = W_e1[(size_t)(k4 * 4 + 1) * HDIM + t];
            float w2 = W_e1[(size_t)(k4 * 4 + 2) * HDIM + t];
            float w3 = W_e1[(size_t)(k4 * 4 + 3) * HDIM + t];
            float4 x0 = *reinterpret_cast<const float4*>(&sA[0][k4 * 4]);
            float4 x1 = *reinterpret_cast<const float4*>(&sA[1][k4 * 4]);
            float4 x2 = *reinterpret_cast<const float4*>(&sA[2][k4 * 4]);
            float4 x3 = *reinterpret_cast<const float4*>(&sA[3][k4 * 4]);
            a0 += x0.x * w0 + x0.y * w1 + x0.z * w2 + x0.w * w3;
            a1 += x1.x * w0 + x1.y * w1 + x1.z * w2 + x1.w * w3;
            a2 += x2.x * w0 + x2.y * w1 + x2.z * w2 + x2.w * w3;
            a3 += x3.x * w0 + x3.y * w1 + x3.z * w2 + x3.w * w3;
        }
        pW1[(size_t)r[0] * HDIM + t] = 0.5f * a0;
        pW1[(size_t)r[1] * HDIM + t] = 0.5f * a1;
        pW1[(size_t)r[2] * HDIM + t] = 0.5f * a2;
        pW1[(size_t)r[3] * HDIM + t] = 0.5f * a3;
    }
}

// ============ k_nl: [256,512]@[512,1600]+b, 8 batches/block ================
__global__ __launch_bounds__(320) void k_nl(const float* __restrict__ n1,
                                            const float* __restrict__ W_n2,
                                            const float* __restrict__ b_n2,
                                            float* __restrict__ out_nl) {
    const int NOUT = NDIM * DDIM;   // 1600
    int t = threadIdx.x;
    int j = blockIdx.y * 320 + t;
    int bg = blockIdx.x;            // 8 batches
    __shared__ float s[8 * HDIM];
    for (int idx = t; idx < 8 * HDIM / 4; idx += 320) {
        int lin = idx * 4;
        int row = lin >> 9, col = lin & 511;
        *reinterpret_cast<float4*>(&s[row * HDIM + col]) =
            *reinterpret_cast<const float4*>(&n1[(size_t)(bg * 8 + row) * HDIM + col]);
    }
    __syncthreads();
    float bias = b_n2[j];
    float acc[8];
#pragma unroll
    for (int b = 0; b < 8; ++b) acc[b] = bias;
    for (int k4 = 0; k4 < HDIM / 4; ++k4) {
        float w0 = W_n2[(size_t)(k4 * 4 + 0) * NOUT + j];
        float w1 = W_n2[(size_t)(k4 * 4 + 1) * NOUT + j];
        float w2 = W_n2[(size_t)(k4 * 4 + 2) * NOUT + j];
        float w3 = W_n2[(size_t)(k4 * 4 + 3) * NOUT + j];
#pragma unroll
        for (int b = 0; b < 8; ++b) {
            float4 nv = *reinterpret_cast<const float4*>(&s[b * HDIM + k4 * 4]);
            acc[b] += nv.x * w0 + nv.y * w1 + nv.z * w2 + nv.w * w3;
        }
    }
#pragma unroll
    for (int b = 0; b < 8; ++b)
        out_nl[(size_t)(bg * 8 + b) * NOUT + j] = acc[b];
}

// ============ k_edge: round-6 structure + produce-ILP fix ==================
// grid (256,2), block 256, LDS 51.2KB. Produce: thread owns (arr, col),
// 50 rows, 4 independent FMA chains per row. Consume: 225 tasks of 2x3 tiles.
__global__ __launch_bounds__(256) void k_edge(
        const float* __restrict__ nl,    // [256,50,32]
        const float* __restrict__ u,     // [256,512]
        const float* __restrict__ pW1,   // [50,512]
        const float* __restrict__ W_e1,  // [576,512]
        const float* __restrict__ b_e1,  // [512]
        const float* __restrict__ W_e2,  // [512,5]
        float* __restrict__ P) {         // [2][256][1225][5]
    int b  = blockIdx.x;
    int rh = blockIdx.y;
    int t  = threadIdx.x;
    int rbase = rh * 256;

    __shared__ float As[NDIM * ECH];   // 25.6 KB
    __shared__ float Bs[NDIM * ECH];   // 25.6 KB

    // task decode: (p,q): rows i0=2p,i0+1; cols j0=3q..3q+2; 225 valid tiles
    bool has = (t < 225);
    int pp = 0, qq = 0;
    if (has) {
        int tt = t;
        for (pp = 0; pp < 25; ++pp) {
            int qmin = pp ? ((2 * pp - 2) / 3 + 1) : 0;
            int cnt = 17 - qmin;
            if (tt < cnt) { qq = qmin + tt; break; }
            tt -= cnt;
        }
    }
    int i0 = 2 * pp, i1 = i0 + 1;
    int j0 = 3 * qq, j1 = j0 + 1, j2r = (3 * qq + 2 < NDIM) ? 3 * qq + 2 : NDIM - 1;

    float acc[6][EOUT];
#pragma unroll
    for (int e = 0; e < 6; ++e)
#pragma unroll
        for (int o = 0; o < EOUT; ++o) acc[e][o] = 0.f;

    // produce role: c = t&127, arr = t>>7; 50 rows each
    int c = t & 127, arr = t >> 7;
    const float4* nl4 = reinterpret_cast<const float4*>(nl + (size_t)b * (NDIM * DDIM));

    for (int ch = 0; ch < 2; ++ch) {
        int col = rbase + ch * ECH + c;
        // ---- produce (4 independent FMA chains per row) ----
        {
            float w[DDIM];
#pragma unroll
            for (int k = 0; k < DDIM; ++k)
                w[k] = W_e1[(size_t)(HDIM + arr * DDIM + k) * HDIM + col];
            float cm = 0.5f * (u[(size_t)b * HDIM + col] + b_e1[col]);
            float* dst = arr ? Bs : As;
            for (int n = 0; n < NDIM; ++n) {
                float p0 = pW1[(size_t)n * HDIM + col];
                float s0 = 0.f, s1 = 0.f, s2 = 0.f, s3 = 0.f;
#pragma unroll
                for (int h = 0; h < 2; ++h) {
                    int q = h * 4;
                    float4 xA = nl4[n * 8 + q + 0];
                    float4 xB = nl4[n * 8 + q + 1];
                    float4 xC = nl4[n * 8 + q + 2];
                    float4 xD = nl4[n * 8 + q + 3];
                    s0 += xA.x * w[4*q+0]  + xA.y * w[4*q+1]  + xA.z * w[4*q+2]  + xA.w * w[4*q+3];
                    s1 += xB.x * w[4*q+4]  + xB.y * w[4*q+5]  + xB.z * w[4*q+6]  + xB.w * w[4*q+7];
                    s2 += xC.x * w[4*q+8]  + xC.y * w[4*q+9]  + xC.z * w[4*q+10] + xC.w * w[4*q+11];
                    s3 += xD.x * w[4*q+12] + xD.y * w[4*q+13] + xD.z * w[4*q+14] + xD.w * w[4*q+15];
                }
                dst[n * ECH + ((((c >> 2) ^ (n & 7)) << 2) | (c & 3))] =
                    (cm + p0) + ((s0 + s1) + (s2 + s3));
            }
        }
        __syncthreads();
        // ---- consume ----
        if (has) {
            const float4* A4 = reinterpret_cast<const float4*>(As);
            const float4* B4 = reinterpret_cast<const float4*>(Bs);
            const float* wch = W_e2 + (size_t)(rbase + ch * ECH) * EOUT;
            for (int r4 = 0; r4 < ECH / 4; ++r4) {
                const float* wr = wch + r4 * 4 * EOUT;   // uniform -> s_load
                float4 a0 = A4[i0 * 32 + (r4 ^ (i0 & 7))];
                float4 a1 = A4[i1 * 32 + (r4 ^ (i1 & 7))];
                float4 b0 = B4[j0 * 32 + (r4 ^ (j0 & 7))];
                float4 b1 = B4[j1 * 32 + (r4 ^ (j1 & 7))];
                float4 b2 = B4[j2r * 32 + (r4 ^ (j2r & 7))];
                float v[6][4];
#pragma unroll
                for (int rr = 0; rr < 4; ++rr) {
                    float av0 = (&a0.x)[rr], av1 = (&a1.x)[rr];
                    float bv0 = (&b0.x)[rr], bv1 = (&b1.x)[rr], bv2 = (&b2.x)[rr];
                    v[0][rr] = fmaxf(av0 + bv0, 0.f);
                    v[1][rr] = fmaxf(av0 + bv1, 0.f);
                    v[2][rr] = fmaxf(av0 + bv2, 0.f);
                    v[3][rr] = fmaxf(av1 + bv0, 0.f);
                    v[4][rr] = fmaxf(av1 + bv1, 0.f);
                    v[5][rr] = fmaxf(av1 + bv2, 0.f);
                }
#pragma unroll
                for (int rr = 0; rr < 4; ++rr) {
#pragma unroll
                    for (int o = 0; o < EOUT; ++o) {
                        float wv = wr[rr * EOUT + o];
#pragma unroll
                        for (int e = 0; e < 6; ++e)
                            acc[e][o] += v[e][rr] * wv;
                    }
                }
            }
        }
        __syncthreads();
    }

    if (has) {
        float* Pb = P + ((size_t)rh * BSZ + b) * NEDGE * EOUT;
        int js[3] = {j0, j1, 3 * qq + 2};
#pragma unroll
        for (int r = 0; r < 2; ++r) {
            int i = i0 + r;
#pragma unroll
            for (int cc = 0; cc < 3; ++cc) {
                int j = js[cc];
                if (i < j && j < NDIM) {
                    int e = i * (NDIM - 1) - (i * (i - 1)) / 2 + (j - i - 1);
#pragma unroll
                    for (int o = 0; o < EOUT; ++o)
                        Pb[(size_t)e * EOUT + o] = acc[r * 3 + cc][o];
                }
            }
        }
    }
}

// ============ k_comb: out_el = P0+P1 + bias (float4 x5/thread) =============
__global__ __launch_bounds__(256) void k_comb(const float* __restrict__ P,
                                              const float* __restrict__ b_e2,
                                              float* __restrict__ out_el,
                                              float* __restrict__ out_idx) {
    int blk = blockIdx.x, t = threadIdx.x;
    const size_t PS = (size_t)BSZ * NEDGE * EOUT;
    if (blk < 307) {
        int tid = blk * 256 + t;       // 20 floats per thread; 78400 total
        if (tid < 78400) {
            const float4* p0 = reinterpret_cast<const float4*>(P) + (size_t)tid * 5;
            const float4* p1 = reinterpret_cast<const float4*>(P + PS) + (size_t)tid * 5;
            float4* o = reinterpret_cast<float4*>(out_el) + (size_t)tid * 5;
            float b5[5];
#pragma unroll
            for (int cc = 0; cc < 5; ++cc) b5[cc] = b_e2[cc];
#pragma unroll
            for (int q = 0; q < 5; ++q) {
                float4 a = p0[q], b = p1[q];
                float4 r;
                r.x = a.x + b.x + b5[(q * 4 + 0) % 5];
                r.y = a.y + b.y + b5[(q * 4 + 1) % 5];
                r.z = a.z + b.z + b5[(q * 4 + 2) % 5];
                r.w = a.w + b.w + b5[(q * 4 + 3) % 5];
                o[q] = r;
            }
        }
    } else {
        int e = (blk - 307) * 256 + t;
        if (e < NEDGE) {
            int i = 0, rem = e;
            while (rem >= (NDIM - 1 - i)) { rem -= (NDIM - 1 - i); ++i; }
            int j = i + 1 + rem;
            out_idx[e * 2] = (float)i;
            out_idx[e * 2 + 1] = (float)j;
        }
    }
}

extern "C" void kernel_launch(void* const* d_in, const int* in_sizes, int n_in,
                              void* d_out, int out_size, void* d_ws, size_t ws_size,
                              hipStream_t stream) {
    const float* z    = (const float*)d_in[0];
    const float* tp   = (const float*)d_in[1];
    const float* W_in = (const float*)d_in[2];
    const float* b_in = (const float*)d_in[3];
    const float* W_s1 = (const float*)d_in[4];
    const float* b_s1 = (const float*)d_in[5];
    const float* W_s2 = (const float*)d_in[6];
    const float* b_s2 = (const float*)d_in[7];
    const float* W_n1 = (const float*)d_in[8];
    const float* b_n1 = (const float*)d_in[9];
    const float* W_n2 = (const float*)d_in[10];
    const float* b_n2 = (const float*)d_in[11];
    const float* W_e1 = (const float*)d_in[12];
    const float* b_e1 = (const float*)d_in[13];
    const float* W_e2 = (const float*)d_in[14];
    const float* b_e2 = (const float*)d_in[15];
    const float* pe   = (const float*)d_in[16];

    float* out     = (float*)d_out;
    float* out_nl  = out;                 // node_logits
    float* out_el  = out + 409600;        // edge_logits
    float* out_sp  = out + 1977600;       // size_probs
    float* out_idx = out + 1990400;       // edge_indices (as float)

    float* ws  = (float*)d_ws;
    float* u   = ws;
    float* pW1 = ws + 131072;
    float* n1  = ws + 156672;
    float* P   = ws + 287744;             // [2][256][1225][5]

    k_pre<<<333, 512, 0, stream>>>(z, tp, W_in, b_in, W_s1, b_s1, W_s2, b_s2,
                                   W_n1, b_n1, W_e1, pe, n1, u, pW1, out_sp);
    k_nl<<<dim3(32, 5), 320, 0, stream>>>(n1, W_n2, b_n2, out_nl);
    k_edge<<<dim3(BSZ, 2), 256, 0, stream>>>(out_nl, u, pW1, W_e1, b_e1, W_e2, P);
    k_comb<<<312, 256, 0, stream>>>(P, b_e2, out_el, out_idx);
}

// Round 11
// 142.893 us; speedup vs baseline: 2.0527x; 1.2988x over previous
//
#include <hip/hip_runtime.h>
#include <math.h>

// Problem dims
#define BSZ   256
#define LDIM  128
#define PDIM  3
#define HDIM  512
#define DDIM  32
#define NDIM  50
#define NEDGE 1225   // N*(N-1)/2
#define EOUT  5      // EDIM+1
#define NRH   3      // r-splits: cols {192,192,128}

// out layout (floats)
//   node_logits  [256,50,32]   @ 0        (409600)
//   edge_logits  [256,1225,5]  @ 409600   (1568000)
//   size_probs   [256,50]      @ 1977600  (12800)
//   edge_indices [1225,2]      @ 1990400  (2450, float values)
// ws layout (floats): u @0 (131072), pW1 @131072 (25600), n1 @156672 (131072),
//                     P @287744 (3 x 1568000)

// ============ k_pre: 256-thr blocks, col-split roles =======================
// grid 666: [0,256) n1 (2b x 256-col half), [256,512) u, [512,640) size (2b),
//           [640,666) pW1 (4 rows x 256-col half)
__global__ __launch_bounds__(256) void k_pre(
        const float* __restrict__ z, const float* __restrict__ tp,
        const float* __restrict__ W_in, const float* __restrict__ b_in,
        const float* __restrict__ W_s1, const float* __restrict__ b_s1,
        const float* __restrict__ W_s2, const float* __restrict__ b_s2,
        const float* __restrict__ W_n1, const float* __restrict__ b_n1,
        const float* __restrict__ W_e1, const float* __restrict__ pe,
        float* __restrict__ n1, float* __restrict__ u,
        float* __restrict__ pW1, float* __restrict__ out_sp) {
    int bx = blockIdx.x, t = threadIdx.x;
    __shared__ float smem[2368];   // max: sin 264 + sh 1024 + s1 512 + lg 100

    if (bx < 512) {
        // ---- role n1 (bx<256) or u: 2 batches, one 256-col half -----------
        int role = bx >> 8;
        int idx2 = bx & 255;
        int bg = idx2 >> 1, jh = idx2 & 1;
        int b0 = bg * 2;
        float* sin_ = smem;            // [2][132]
        float* sh   = smem + 264;      // [2][512]
        for (int q = t; q < 2 * 131; q += 256) {
            int bi = q / 131, k = q % 131;
            sin_[bi * 132 + k] = (k < LDIM) ? z[(size_t)(b0 + bi) * LDIM + k]
                                            : tp[(size_t)(b0 + bi) * PDIM + (k - LDIM)];
        }
        __syncthreads();
        {
            float bi0 = b_in[t], bi1 = b_in[t + 256];
            float a00 = bi0, a01 = bi1, a10 = bi0, a11 = bi1;
            for (int k = 0; k < LDIM + PDIM; ++k) {
                float w0 = W_in[(size_t)k * HDIM + t];
                float w1 = W_in[(size_t)k * HDIM + t + 256];
                float x0 = sin_[k], x1 = sin_[132 + k];
                a00 += x0 * w0; a01 += x0 * w1;
                a10 += x1 * w0; a11 += x1 * w1;
            }
            sh[t] = fmaxf(a00, 0.f); sh[t + 256] = fmaxf(a01, 0.f);
            sh[512 + t] = fmaxf(a10, 0.f); sh[512 + t + 256] = fmaxf(a11, 0.f);
        }
        __syncthreads();
        int j = jh * 256 + t;
        const float* W = role ? W_e1 : W_n1;   // W1h = rows 0..511 of W_e1
        float s0a = 0.f, s0b = 0.f, s1a = 0.f, s1b = 0.f;
        for (int k4 = 0; k4 < HDIM / 4; ++k4) {
            float w0 = W[(size_t)(k4 * 4 + 0) * HDIM + j];
            float w1 = W[(size_t)(k4 * 4 + 1) * HDIM + j];
            float w2 = W[(size_t)(k4 * 4 + 2) * HDIM + j];
            float w3 = W[(size_t)(k4 * 4 + 3) * HDIM + j];
            float4 x0 = *reinterpret_cast<const float4*>(&sh[k4 * 4]);
            float4 x1 = *reinterpret_cast<const float4*>(&sh[512 + k4 * 4]);
            s0a += x0.x * w0 + x0.y * w1;
            s0b += x0.z * w2 + x0.w * w3;
            s1a += x1.x * w0 + x1.y * w1;
            s1b += x1.z * w2 + x1.w * w3;
        }
        float a0 = s0a + s0b, a1 = s1a + s1b;
        if (role == 0) {
            float bb = b_n1[j];
            n1[(size_t)(b0 + 0) * HDIM + j] = fmaxf(a0 + bb, 0.f);
            n1[(size_t)(b0 + 1) * HDIM + j] = fmaxf(a1 + bb, 0.f);
        } else {
            u[(size_t)(b0 + 0) * HDIM + j] = a0;
            u[(size_t)(b0 + 1) * HDIM + j] = a1;
        }
    } else if (bx < 640) {
        // ---- role size head: 2 batches ------------------------------------
        int b0 = (bx - 512) * 2;
        float* sin_ = smem;            // [2][132]
        float* sh   = smem + 264;      // [2][512]
        float* s1b  = smem + 264 + 1024;  // [2][256]
        float* slg  = smem + 264 + 1024 + 512;  // [2][50]
        for (int q = t; q < 2 * 131; q += 256) {
            int bi = q / 131, k = q % 131;
            sin_[bi * 132 + k] = (k < LDIM) ? z[(size_t)(b0 + bi) * LDIM + k]
                                            : tp[(size_t)(b0 + bi) * PDIM + (k - LDIM)];
        }
        __syncthreads();
        {
            float bi0 = b_in[t], bi1 = b_in[t + 256];
            float a00 = bi0, a01 = bi1, a10 = bi0, a11 = bi1;
            for (int k = 0; k < LDIM + PDIM; ++k) {
                float w0 = W_in[(size_t)k * HDIM + t];
                float w1 = W_in[(size_t)k * HDIM + t + 256];
                float x0 = sin_[k], x1 = sin_[132 + k];
                a00 += x0 * w0; a01 += x0 * w1;
                a10 += x1 * w0; a11 += x1 * w1;
            }
            sh[t] = fmaxf(a00, 0.f); sh[t + 256] = fmaxf(a01, 0.f);
            sh[512 + t] = fmaxf(a10, 0.f); sh[512 + t + 256] = fmaxf(a11, 0.f);
        }
        __syncthreads();
        {
            float bv = b_s1[t];
            float a0 = bv, a1 = bv;
            for (int k = 0; k < HDIM; ++k) {
                float w = W_s1[(size_t)k * (HDIM / 2) + t];
                a0 += sh[k] * w;
                a1 += sh[512 + k] * w;
            }
            s1b[t] = fmaxf(a0, 0.f);
            s1b[256 + t] = fmaxf(a1, 0.f);
        }
        __syncthreads();
        int b4 = t / NDIM, o = t % NDIM;
        if (t < 2 * NDIM) {
            float a = b_s2[o];
            for (int k = 0; k < HDIM / 2; ++k)
                a += s1b[b4 * 256 + k] * W_s2[(size_t)k * NDIM + o];
            slg[b4 * NDIM + o] = a;
        }
        __syncthreads();
        if (t < 2 * NDIM) {
            float m = slg[b4 * NDIM];
            for (int k = 1; k < NDIM; ++k) m = fmaxf(m, slg[b4 * NDIM + k]);
            float s = 0.f;
            for (int k = 0; k < NDIM; ++k) s += expf(slg[b4 * NDIM + k] - m);
            out_sp[(size_t)(b0 + b4) * NDIM + o] = expf(slg[b4 * NDIM + o] - m) / s;
        }
    } else {
        // ---- role pW1: 0.5 * pe @ W1h, 4 rows x 256-col half --------------
        int g = bx - 640, rg = g >> 1, jh = g & 1;
        int r[4];
#pragma unroll
        for (int q = 0; q < 4; ++q) { int rr = rg * 4 + q; r[q] = (rr < NDIM) ? rr : NDIM - 1; }
        float* spe = smem;   // [4][512]
        for (int q = t; q < 4 * HDIM / 4; q += 256) {
            int lin = q * 4, row = lin >> 9, col = lin & 511;
            *reinterpret_cast<float4*>(&spe[row * HDIM + col]) =
                *reinterpret_cast<const float4*>(&pe[(size_t)r[row] * HDIM + col]);
        }
        __syncthreads();
        int j = jh * 256 + t;
        float a0 = 0.f, a1 = 0.f, a2 = 0.f, a3 = 0.f;
        for (int k4 = 0; k4 < HDIM / 4; ++k4) {
            float w0 = W_e1[(size_t)(k4 * 4 + 0) * HDIM + j];
            float w1 = W_e1[(size_t)(k4 * 4 + 1) * HDIM + j];
            float w2 = W_e1[(size_t)(k4 * 4 + 2) * HDIM + j];
            float w3 = W_e1[(size_t)(k4 * 4 + 3) * HDIM + j];
            float4 x0 = *reinterpret_cast<const float4*>(&spe[0 * HDIM + k4 * 4]);
            float4 x1 = *reinterpret_cast<const float4*>(&spe[1 * HDIM + k4 * 4]);
            float4 x2 = *reinterpret_cast<const float4*>(&spe[2 * HDIM + k4 * 4]);
            float4 x3 = *reinterpret_cast<const float4*>(&spe[3 * HDIM + k4 * 4]);
            a0 += x0.x * w0 + x0.y * w1 + x0.z * w2 + x0.w * w3;
            a1 += x1.x * w0 + x1.y * w1 + x1.z * w2 + x1.w * w3;
            a2 += x2.x * w0 + x2.y * w1 + x2.z * w2 + x2.w * w3;
            a3 += x3.x * w0 + x3.y * w1 + x3.z * w2 + x3.w * w3;
        }
        pW1[(size_t)r[0] * HDIM + j] = 0.5f * a0;
        pW1[(size_t)r[1] * HDIM + j] = 0.5f * a1;
        pW1[(size_t)r[2] * HDIM + j] = 0.5f * a2;
        pW1[(size_t)r[3] * HDIM + j] = 0.5f * a3;
    }
}

// ============ k_nl: [256,512]@[512,1600]+b, 2 batches/block ================
// grid (128,5) = 640 blocks -> ~2.5 blocks/CU.
__global__ __launch_bounds__(320) void k_nl(const float* __restrict__ n1,
                                            const float* __restrict__ W_n2,
                                            const float* __restrict__ b_n2,
                                            float* __restrict__ out_nl) {
    const int NOUT = NDIM * DDIM;   // 1600
    int t = threadIdx.x;
    int j = blockIdx.y * 320 + t;
    int bg = blockIdx.x;            // 2 batches
    __shared__ float s[2 * HDIM];
    for (int idx = t; idx < 2 * HDIM / 4; idx += 320) {
        int lin = idx * 4;
        int row = lin >> 9, col = lin & 511;
        *reinterpret_cast<float4*>(&s[row * HDIM + col]) =
            *reinterpret_cast<const float4*>(&n1[(size_t)(bg * 2 + row) * HDIM + col]);
    }
    __syncthreads();
    float s0a = 0.f, s0b = 0.f, s1a = 0.f, s1b = 0.f;
    for (int k4 = 0; k4 < HDIM / 4; ++k4) {
        float w0 = W_n2[(size_t)(k4 * 4 + 0) * NOUT + j];
        float w1 = W_n2[(size_t)(k4 * 4 + 1) * NOUT + j];
        float w2 = W_n2[(size_t)(k4 * 4 + 2) * NOUT + j];
        float w3 = W_n2[(size_t)(k4 * 4 + 3) * NOUT + j];
        float4 x0 = *reinterpret_cast<const float4*>(&s[k4 * 4]);
        float4 x1 = *reinterpret_cast<const float4*>(&s[HDIM + k4 * 4]);
        s0a += x0.x * w0 + x0.y * w1;
        s0b += x0.z * w2 + x0.w * w3;
        s1a += x1.x * w0 + x1.y * w1;
        s1b += x1.z * w2 + x1.w * w3;
    }
    float bias = b_n2[j];
    out_nl[(size_t)(bg * 2 + 0) * NOUT + j] = bias + s0a + s0b;
    out_nl[(size_t)(bg * 2 + 1) * NOUT + j] = bias + s1a + s1b;
}

// ============ k_edge: 3-way r-split {192,192,128}, chunks of 96/64 =========
// grid (256,3) = 768 blocks, block 256, LDS 38.4KB -> exactly 3 blocks/CU.
__global__ __launch_bounds__(256) void k_edge(
        const float* __restrict__ nl,    // [256,50,32]
        const float* __restrict__ u,     // [256,512]
        const float* __restrict__ pW1,   // [50,512]
        const float* __restrict__ W_e1,  // [576,512]
        const float* __restrict__ b_e1,  // [512]
        const float* __restrict__ W_e2,  // [512,5]
        float* __restrict__ P) {         // [3][256][1225][5]
    int b  = blockIdx.x;
    int rh = blockIdx.y;
    int t  = threadIdx.x;
    int rbase = rh * 192;
    int ECH = (rh < 2) ? 96 : 64;       // chunk cols (2 chunks per block)
    int ech4 = ECH >> 2;

    __shared__ float As[NDIM * 96];   // 19.2 KB
    __shared__ float Bs[NDIM * 96];   // 19.2 KB

    // task decode: (p,q): rows i0=2p,i0+1; cols j0=3q..3q+2; 225 valid tiles
    bool has = (t < 225);
    int pp = 0, qq = 0;
    if (has) {
        int tt = t;
        for (pp = 0; pp < 25; ++pp) {
            int qmin = pp ? ((2 * pp - 2) / 3 + 1) : 0;
            int cnt = 17 - qmin;
            if (tt < cnt) { qq = qmin + tt; break; }
            tt -= cnt;
        }
    }
    int i0 = 2 * pp, i1 = i0 + 1;
    int j0 = 3 * qq, j1 = j0 + 1, j2r = (3 * qq + 2 < NDIM) ? 3 * qq + 2 : NDIM - 1;

    float acc[6][EOUT];
#pragma unroll
    for (int e = 0; e < 6; ++e)
#pragma unroll
        for (int o = 0; o < EOUT; ++o) acc[e][o] = 0.f;

    // produce role: threads [0, 2*ECH): arr = t/ECH, c = t%ECH
    bool prod = (t < 2 * ECH);
    int arr = (t >= ECH) ? 1 : 0;
    int c = t - (arr ? ECH : 0);
    const float4* nl4 = reinterpret_cast<const float4*>(nl + (size_t)b * (NDIM * DDIM));

    for (int ch = 0; ch < 2; ++ch) {
        // ---- produce ----
        if (prod) {
            int col = rbase + ch * ECH + c;
            float w[DDIM];
#pragma unroll
            for (int k = 0; k < DDIM; ++k)
                w[k] = W_e1[(size_t)(HDIM + arr * DDIM + k) * HDIM + col];
            float cm = 0.5f * (u[(size_t)b * HDIM + col] + b_e1[col]);
            float* dst = arr ? Bs : As;
            float pc = pW1[col];   // row 0, rotate-prefetched
            for (int n = 0; n < NDIM; ++n) {
                float pn = (n < NDIM - 1) ? pW1[(size_t)(n + 1) * HDIM + col] : 0.f;
                float s0 = 0.f, s1 = 0.f, s2 = 0.f, s3 = 0.f;
#pragma unroll
                for (int h = 0; h < 2; ++h) {
                    int q = h * 4;
                    float4 xA = nl4[n * 8 + q + 0];
                    float4 xB = nl4[n * 8 + q + 1];
                    float4 xC = nl4[n * 8 + q + 2];
                    float4 xD = nl4[n * 8 + q + 3];
                    s0 += xA.x * w[4*q+0]  + xA.y * w[4*q+1]  + xA.z * w[4*q+2]  + xA.w * w[4*q+3];
                    s1 += xB.x * w[4*q+4]  + xB.y * w[4*q+5]  + xB.z * w[4*q+6]  + xB.w * w[4*q+7];
                    s2 += xC.x * w[4*q+8]  + xC.y * w[4*q+9]  + xC.z * w[4*q+10] + xC.w * w[4*q+11];
                    s3 += xD.x * w[4*q+12] + xD.y * w[4*q+13] + xD.z * w[4*q+14] + xD.w * w[4*q+15];
                }
                dst[n * ECH + ((((c >> 2) ^ (n & 7)) << 2) | (c & 3))] =
                    (cm + pc) + ((s0 + s1) + (s2 + s3));
                pc = pn;
            }
        }
        __syncthreads();
        // ---- consume ----
        if (has) {
            const float4* A4 = reinterpret_cast<const float4*>(As);
            const float4* B4 = reinterpret_cast<const float4*>(Bs);
            const float* wch = W_e2 + (size_t)(rbase + ch * ECH) * EOUT;
            int iA = i0 * ech4, iB = i1 * ech4;
            int jA = j0 * ech4, jB = j1 * ech4, jC = j2r * ech4;
            int sA = i0 & 7, sB = i1 & 7, s0m = j0 & 7, s1m = j1 & 7, s2m = j2r & 7;
            for (int r4 = 0; r4 < ech4; ++r4) {
                const float* wr = wch + r4 * 4 * EOUT;   // uniform -> s_load
                float4 a0 = A4[iA + (r4 ^ sA)];
                float4 a1 = A4[iB + (r4 ^ sB)];
                float4 b0 = B4[jA + (r4 ^ s0m)];
                float4 b1 = B4[jB + (r4 ^ s1m)];
                float4 b2 = B4[jC + (r4 ^ s2m)];
                float v[6][4];
#pragma unroll
                for (int rr = 0; rr < 4; ++rr) {
                    float av0 = (&a0.x)[rr], av1 = (&a1.x)[rr];
                    float bv0 = (&b0.x)[rr], bv1 = (&b1.x)[rr], bv2 = (&b2.x)[rr];
                    v[0][rr] = fmaxf(av0 + bv0, 0.f);
                    v[1][rr] = fmaxf(av0 + bv1, 0.f);
                    v[2][rr] = fmaxf(av0 + bv2, 0.f);
                    v[3][rr] = fmaxf(av1 + bv0, 0.f);
                    v[4][rr] = fmaxf(av1 + bv1, 0.f);
                    v[5][rr] = fmaxf(av1 + bv2, 0.f);
                }
#pragma unroll
                for (int rr = 0; rr < 4; ++rr) {
#pragma unroll
                    for (int o = 0; o < EOUT; ++o) {
                        float wv = wr[rr * EOUT + o];
#pragma unroll
                        for (int e = 0; e < 6; ++e)
                            acc[e][o] += v[e][rr] * wv;
                    }
                }
            }
        }
        __syncthreads();
    }

    if (has) {
        float* Pb = P + ((size_t)rh * BSZ + b) * NEDGE * EOUT;
        int js[3] = {j0, j1, 3 * qq + 2};
#pragma unroll
        for (int r = 0; r < 2; ++r) {
            int i = i0 + r;
#pragma unroll
            for (int cc = 0; cc < 3; ++cc) {
                int j = js[cc];
                if (i < j && j < NDIM) {
                    int e = i * (NDIM - 1) - (i * (i - 1)) / 2 + (j - i - 1);
#pragma unroll
                    for (int o = 0; o < EOUT; ++o)
                        Pb[(size_t)e * EOUT + o] = acc[r * 3 + cc][o];
                }
            }
        }
    }
}

// ============ k_comb: out_el = P0+P1+P2 + bias (float4 x5/thread) ==========
__global__ __launch_bounds__(256) void k_comb(const float* __restrict__ P,
                                              const float* __restrict__ b_e2,
                                              float* __restrict__ out_el,
                                              float* __restrict__ out_idx) {
    int blk = blockIdx.x, t = threadIdx.x;
    const size_t PS = (size_t)BSZ * NEDGE * EOUT;
    if (blk < 307) {
        int tid = blk * 256 + t;       // 20 floats per thread; 78400 total
        if (tid < 78400) {
            const float4* p0 = reinterpret_cast<const float4*>(P) + (size_t)tid * 5;
            const float4* p1 = reinterpret_cast<const float4*>(P + PS) + (size_t)tid * 5;
            const float4* p2 = reinterpret_cast<const float4*>(P + 2 * PS) + (size_t)tid * 5;
            float4* o = reinterpret_cast<float4*>(out_el) + (size_t)tid * 5;
            float b5[5];
#pragma unroll
            for (int cc = 0; cc < 5; ++cc) b5[cc] = b_e2[cc];
#pragma unroll
            for (int q = 0; q < 5; ++q) {
                float4 a = p0[q], b = p1[q], cq = p2[q];
                float4 r;
                r.x = a.x + b.x + cq.x + b5[(q * 4 + 0) % 5];
                r.y = a.y + b.y + cq.y + b5[(q * 4 + 1) % 5];
                r.z = a.z + b.z + cq.z + b5[(q * 4 + 2) % 5];
                r.w = a.w + b.w + cq.w + b5[(q * 4 + 3) % 5];
                o[q] = r;
            }
        }
    } else {
        int e = (blk - 307) * 256 + t;
        if (e < NEDGE) {
            int i = 0, rem = e;
            while (rem >= (NDIM - 1 - i)) { rem -= (NDIM - 1 - i); ++i; }
            int j = i + 1 + rem;
            out_idx[e * 2] = (float)i;
            out_idx[e * 2 + 1] = (float)j;
        }
    }
}

extern "C" void kernel_launch(void* const* d_in, const int* in_sizes, int n_in,
                              void* d_out, int out_size, void* d_ws, size_t ws_size,
                              hipStream_t stream) {
    const float* z    = (const float*)d_in[0];
    const float* tp   = (const float*)d_in[1];
    const float* W_in = (const float*)d_in[2];
    const float* b_in = (const float*)d_in[3];
    const float* W_s1 = (const float*)d_in[4];
    const float* b_s1 = (const float*)d_in[5];
    const float* W_s2 = (const float*)d_in[6];
    const float* b_s2 = (const float*)d_in[7];
    const float* W_n1 = (const float*)d_in[8];
    const float* b_n1 = (const float*)d_in[9];
    const float* W_n2 = (const float*)d_in[10];
    const float* b_n2 = (const float*)d_in[11];
    const float* W_e1 = (const float*)d_in[12];
    const float* b_e1 = (const float*)d_in[13];
    const float* W_e2 = (const float*)d_in[14];
    const float* b_e2 = (const float*)d_in[15];
    const float* pe   = (const float*)d_in[16];

    float* out     = (float*)d_out;
    float* out_nl  = out;                 // node_logits
    float* out_el  = out + 409600;        // edge_logits
    float* out_sp  = out + 1977600;       // size_probs
    float* out_idx = out + 1990400;       // edge_indices (as float)

    float* ws  = (float*)d_ws;
    float* u   = ws;
    float* pW1 = ws + 131072;
    float* n1  = ws + 156672;
    float* P   = ws + 287744;             // [3][256][1225][5]

    k_pre<<<666, 256, 0, stream>>>(z, tp, W_in, b_in, W_s1, b_s1, W_s2, b_s2,
                                   W_n1, b_n1, W_e1, pe, n1, u, pW1, out_sp);
    k_nl<<<dim3(128, 5), 320, 0, stream>>>(n1, W_n2, b_n2, out_nl);
    k_edge<<<dim3(BSZ, NRH), 256, 0, stream>>>(out_nl, u, pW1, W_e1, b_e1, W_e2, P);
    k_comb<<<312, 256, 0, stream>>>(P, b_e2, out_el, out_idx);
}